// Round 1
// baseline (203.657 us; speedup 1.0000x reference)
//
#include <hip/hip_runtime.h>
#include <hip/hip_bf16.h>
#include <type_traits>

// Problem dims (fixed by setup_inputs): B=8, L=2048, T=1024, Dh=1024, Dg=768, Dp=256
// Pipeline: HT=cast(H^T); Q=G@Wq^T; K=H@Wk^T; S=softmax(Q@K^T/16); Z=S@H
// Workspace layout (needs 76 MB):
//   Qbf [B*T*Dp] bf16 (4MB) | Kbf [B*L*Dp] bf16 (8MB) | HT [B*Dh*L] bf16 (32MB) | S [B*T*L] bf16 (32MB)

typedef float    f32x4  __attribute__((ext_vector_type(4)));
typedef __bf16   bf16x8 __attribute__((ext_vector_type(8)));
typedef unsigned short u16x8 __attribute__((ext_vector_type(8)));

__device__ __forceinline__ unsigned short f2bf(float f) {
    union { float f; unsigned u; } x; x.f = f;
    unsigned r = (x.u + 0x7fffu + ((x.u >> 16) & 1u)) >> 16;
    return (unsigned short)r;
}
__device__ __forceinline__ float bf2f(unsigned short u) {
    union { unsigned u; float f; } x; x.u = ((unsigned)u) << 16;
    return x.f;
}

// ---------------- transpose + cast: H [L,Dh] f32 -> HT [Dh,L] bf16, per batch ----------------
__global__ __launch_bounds__(256) void transpose_cast(const float* __restrict__ H,
                                                      unsigned short* __restrict__ HT,
                                                      int L, int D) {
    __shared__ float tile[32][33];
    int b = blockIdx.z;
    const float* src = H + (size_t)b * L * D;
    unsigned short* dst = HT + (size_t)b * L * D;
    int l0 = blockIdx.y * 32, d0 = blockIdx.x * 32;
    int tx = threadIdx.x, ty = threadIdx.y;
#pragma unroll
    for (int i = ty; i < 32; i += 8)
        tile[i][tx] = src[(size_t)(l0 + i) * D + d0 + tx];
    __syncthreads();
#pragma unroll
    for (int i = ty; i < 32; i += 8)
        dst[(size_t)(d0 + i) * L + l0 + tx] = f2bf(tile[tx][i]);
}

// ---------------- generic GEMM: C[M,N] = scale * A[M,K] @ B^T[N,K] -----------------
// A: f32 or bf16-bits; B: f32 or bf16-bits; C: f32 or bf16-bits.
// 128x128 tile, BK=32, 256 threads = 4 waves (2x2 of 64x64), 16x16x32 bf16 MFMA.

template<typename T>
__device__ __forceinline__ void stage_tile(const T* __restrict__ src, int ld, int k0,
                                           unsigned short* dst, int tid) {
    int row = tid >> 1;
    int col = (tid & 1) * 16;
    const T* p = src + (size_t)row * ld + k0 + col;
    if constexpr (std::is_same_v<T, float>) {
        f32x4 v0 = *(const f32x4*)(p);
        f32x4 v1 = *(const f32x4*)(p + 4);
        f32x4 v2 = *(const f32x4*)(p + 8);
        f32x4 v3 = *(const f32x4*)(p + 12);
        u16x8 o0, o1;
#pragma unroll
        for (int j = 0; j < 4; ++j) {
            o0[j]     = f2bf(v0[j]);
            o0[4 + j] = f2bf(v1[j]);
            o1[j]     = f2bf(v2[j]);
            o1[4 + j] = f2bf(v3[j]);
        }
        *(u16x8*)(&dst[row * 32 + col])     = o0;
        *(u16x8*)(&dst[row * 32 + col + 8]) = o1;
    } else {
        u16x8 v0 = *(const u16x8*)(p);
        u16x8 v1 = *(const u16x8*)(p + 8);
        *(u16x8*)(&dst[row * 32 + col])     = v0;
        *(u16x8*)(&dst[row * 32 + col + 8]) = v1;
    }
}

template<typename TA, typename TB, typename TC>
__global__ __launch_bounds__(256) void gemm_bt(const TA* __restrict__ A,
                                               const TB* __restrict__ B,
                                               TC* __restrict__ C,
                                               int N, int K,
                                               long batchA, long batchB, long batchC,
                                               float scale) {
    __shared__ unsigned short sA[128 * 32];
    __shared__ unsigned short sB[128 * 32];
    int tid = threadIdx.x;
    int bz = blockIdx.z;
    const TA* Ab = A + (size_t)bz * batchA + (size_t)blockIdx.y * 128 * K;
    const TB* Bb = B + (size_t)bz * batchB + (size_t)blockIdx.x * 128 * K;
    TC* Cb = C + (size_t)bz * batchC;
    int brow = blockIdx.y * 128;
    int bcol = blockIdx.x * 128;

    int lane = tid & 63;
    int wid = tid >> 6;
    int wr = wid >> 1, wc = wid & 1;

    f32x4 acc[4][4] = {};

    int lr = lane & 15;
    int lk = (lane >> 4) * 8;

    for (int k0 = 0; k0 < K; k0 += 32) {
        stage_tile<TA>(Ab, K, k0, sA, tid);
        stage_tile<TB>(Bb, K, k0, sB, tid);
        __syncthreads();
        bf16x8 af[4], bfr[4];
#pragma unroll
        for (int m = 0; m < 4; ++m)
            af[m] = *reinterpret_cast<const bf16x8*>(&sA[(wr * 64 + m * 16 + lr) * 32 + lk]);
#pragma unroll
        for (int n = 0; n < 4; ++n)
            bfr[n] = *reinterpret_cast<const bf16x8*>(&sB[(wc * 64 + n * 16 + lr) * 32 + lk]);
#pragma unroll
        for (int m = 0; m < 4; ++m)
#pragma unroll
            for (int n = 0; n < 4; ++n)
                acc[m][n] = __builtin_amdgcn_mfma_f32_16x16x32_bf16(af[m], bfr[n], acc[m][n], 0, 0, 0);
        __syncthreads();
    }

    // epilogue: C/D layout for 16x16x32: col = lane&15, row = (lane>>4)*4 + j
#pragma unroll
    for (int m = 0; m < 4; ++m) {
        int r0 = brow + wr * 64 + m * 16 + (lane >> 4) * 4;
#pragma unroll
        for (int n = 0; n < 4; ++n) {
            int c0 = bcol + wc * 64 + n * 16 + (lane & 15);
#pragma unroll
            for (int j = 0; j < 4; ++j) {
                float v = acc[m][n][j] * scale;
                if constexpr (std::is_same_v<TC, float>)
                    Cb[(size_t)(r0 + j) * N + c0] = v;
                else
                    Cb[(size_t)(r0 + j) * N + c0] = f2bf(v);
            }
        }
    }
}

// ---------------- row softmax in place on bf16 [rows, L=2048], one block per row ----------------
__global__ __launch_bounds__(256) void softmax_inplace(unsigned short* __restrict__ S, int L) {
    __shared__ float red[8];
    size_t row = blockIdx.x;
    unsigned short* p = S + row * (size_t)L;
    int tid = threadIdx.x;
    int lane = tid & 63;
    int wid = tid >> 6;

    u16x8 u = *(const u16x8*)(p + tid * 8);
    float v[8];
#pragma unroll
    for (int j = 0; j < 8; ++j) v[j] = bf2f(u[j]);

    float mx = v[0];
#pragma unroll
    for (int j = 1; j < 8; ++j) mx = fmaxf(mx, v[j]);
#pragma unroll
    for (int off = 32; off > 0; off >>= 1) mx = fmaxf(mx, __shfl_xor(mx, off));
    if (lane == 0) red[wid] = mx;
    __syncthreads();
    mx = fmaxf(fmaxf(red[0], red[1]), fmaxf(red[2], red[3]));

    float s = 0.f;
#pragma unroll
    for (int j = 0; j < 8; ++j) { v[j] = __expf(v[j] - mx); s += v[j]; }
#pragma unroll
    for (int off = 32; off > 0; off >>= 1) s += __shfl_xor(s, off);
    if (lane == 0) red[4 + wid] = s;
    __syncthreads();
    s = red[4] + red[5] + red[6] + red[7];
    float inv = 1.0f / s;

    u16x8 o;
#pragma unroll
    for (int j = 0; j < 8; ++j) o[j] = f2bf(v[j] * inv);
    *(u16x8*)(p + tid * 8) = o;
}

extern "C" void kernel_launch(void* const* d_in, const int* in_sizes, int n_in,
                              void* d_out, int out_size, void* d_ws, size_t ws_size,
                              hipStream_t stream) {
    constexpr int B = 8, L = 2048, T = 1024, Dh = 1024, Dg = 768, Dp = 256;
    const float* H  = (const float*)d_in[0];
    const float* G  = (const float*)d_in[1];
    const float* Wq = (const float*)d_in[2];
    const float* Wk = (const float*)d_in[3];
    float* Z = (float*)d_out;

    unsigned short* Qbf = (unsigned short*)d_ws;            // B*T*Dp
    unsigned short* Kbf = Qbf + (size_t)B * T * Dp;          // B*L*Dp
    unsigned short* HT  = Kbf + (size_t)B * L * Dp;          // B*Dh*L
    unsigned short* S   = HT  + (size_t)B * (size_t)Dh * L;  // B*T*L

    // 1. HT[b,d,l] = bf16(H[b,l,d])
    transpose_cast<<<dim3(Dh / 32, L / 32, B), dim3(32, 8), 0, stream>>>(H, HT, L, Dh);

    // 2. Q = G @ Wq^T   [B*T, Dp], K = Dg
    gemm_bt<float, float, unsigned short>
        <<<dim3(Dp / 128, (B * T) / 128, 1), 256, 0, stream>>>(G, Wq, Qbf, Dp, Dg, 0, 0, 0, 1.0f);

    // 3. K = H @ Wk^T   [B*L, Dp], K = Dh
    gemm_bt<float, float, unsigned short>
        <<<dim3(Dp / 128, (B * L) / 128, 1), 256, 0, stream>>>(H, Wk, Kbf, Dp, Dh, 0, 0, 0, 1.0f);

    // 4. S[b] = Q[b] @ K[b]^T * Dp^-0.5   [T, L], K = Dp
    gemm_bt<unsigned short, unsigned short, unsigned short>
        <<<dim3(L / 128, T / 128, B), 256, 0, stream>>>(Qbf, Kbf, S, L, Dp,
                                                        (long)T * Dp, (long)L * Dp, (long)T * L, 0.0625f);

    // 5. softmax rows of S (in place), B*T rows of length L
    softmax_inplace<<<dim3(B * T), 256, 0, stream>>>(S, L);

    // 6. Z[b] = P[b] @ HT[b]^T   [T, Dh], K = L
    gemm_bt<unsigned short, unsigned short, float>
        <<<dim3(Dh / 128, T / 128, B), 256, 0, stream>>>(S, HT, Z, Dh, L,
                                                         (long)T * L, (long)Dh * L, (long)T * Dh, 1.0f);
}

// Round 2
// 172.430 us; speedup vs baseline: 1.1811x; 1.1811x over previous
//
#include <hip/hip_runtime.h>
#include <hip/hip_bf16.h>
#include <type_traits>

// Dims: B=8, L=2048, T=1024, Dh=1024, Dg=768, Dp=256
// Pipeline (all-bf16 MFMA GEMMs, m97 structure w/ global_load_lds width=16):
//   Gbf,Wqbf,Wkbf = cast(G,Wq,Wk); [HT,Hbf] = transpose+cast(H)
//   Q = Gbf@Wqbf^T; K = Hbf@Wkbf^T; S = softmax(Q@K^T/16); Z = S@HT^T(fp32 out)
// Workspace (u16 elems): Qbf 2M | Kbf 4M | HT 16M | {Hbf|S} 16M | Gbf 6M | Wqbf | Wkbf  ~= 93 MB
// S overlays Hbf: Hbf last read by K-proj (launch 4), S written at launch 5.

typedef float    f32x4  __attribute__((ext_vector_type(4)));
typedef __bf16   bf16x8 __attribute__((ext_vector_type(8)));
typedef unsigned short u16x8 __attribute__((ext_vector_type(8)));

__device__ __forceinline__ unsigned short f2bf(float f) {
    union { float f; unsigned u; } x; x.f = f;
    return (unsigned short)((x.u + 0x7fffu + ((x.u >> 16) & 1u)) >> 16);
}
__device__ __forceinline__ float bf2f(unsigned short u) {
    union { unsigned u; float f; } x; x.u = ((unsigned)u) << 16;
    return x.f;
}

// async global->LDS, 16B per lane. LDS dest must be linear: base + lane*16.
__device__ __forceinline__ void gload_lds16(const unsigned short* g, unsigned short* l) {
    __builtin_amdgcn_global_load_lds(
        (const __attribute__((address_space(1))) void*)g,
        (__attribute__((address_space(3))) void*)l, 16, 0, 0);
}

// ---------------- f32 -> bf16 cast, 8 elems/thread ----------------
__global__ __launch_bounds__(256) void cast_bf16(const float* __restrict__ in,
                                                 unsigned short* __restrict__ out, int n8) {
    int i = blockIdx.x * 256 + threadIdx.x;
    if (i >= n8) return;
    const f32x4* p = (const f32x4*)(in + (size_t)i * 8);
    f32x4 a = p[0], b = p[1];
    u16x8 o;
#pragma unroll
    for (int j = 0; j < 4; ++j) { o[j] = f2bf(a[j]); o[4 + j] = f2bf(b[j]); }
    *(u16x8*)(out + (size_t)i * 8) = o;
}

// ------- transpose + dual cast: H [L,Dh] f32 -> HT [Dh,L] bf16 AND Hbf [L,Dh] bf16 -------
__global__ __launch_bounds__(256) void transpose_cast(const float* __restrict__ H,
                                                      unsigned short* __restrict__ HT,
                                                      unsigned short* __restrict__ Hbf,
                                                      int L, int D) {
    __shared__ float tile[32][33];
    int b = blockIdx.z;
    const float* src = H + (size_t)b * L * D;
    unsigned short* dstT = HT + (size_t)b * L * D;
    unsigned short* dstN = Hbf + (size_t)b * L * D;
    int l0 = blockIdx.y * 32, d0 = blockIdx.x * 32;
    int tx = threadIdx.x, ty = threadIdx.y;
#pragma unroll
    for (int i = ty; i < 32; i += 8) {
        float v = src[(size_t)(l0 + i) * D + d0 + tx];
        tile[i][tx] = v;
        dstN[(size_t)(l0 + i) * D + d0 + tx] = f2bf(v);
    }
    __syncthreads();
#pragma unroll
    for (int i = ty; i < 32; i += 8)
        dstT[(size_t)(d0 + i) * L + l0 + tx] = f2bf(tile[tx][i]);
}

// ---------------- m97-structure GEMM: C[M,N] = scale * A[M,K] @ B^T[N,K] ----------------
// bf16 inputs, 128x128 tile, BK=32, 4 waves, global_load_lds width=16, 2 barriers/K-step.
// Flat 1D grid. BATCH8: batch = wg&7 (XCD-clustered), then by = t>>gxs, bx = t&(gx-1).
template<typename TC, bool BATCH8>
__global__ __launch_bounds__(256) void gemm_lds(const unsigned short* __restrict__ A,
                                                const unsigned short* __restrict__ B,
                                                TC* __restrict__ C,
                                                int N, int K,
                                                long batchA, long batchB, long batchC,
                                                float scale, int gxs) {
    __shared__ unsigned short sA[128 * 32];
    __shared__ unsigned short sB[128 * 32];
    int tid = threadIdx.x;
    int wg = blockIdx.x;
    int bz, t;
    if constexpr (BATCH8) { bz = wg & 7; t = wg >> 3; }
    else                  { bz = 0;      t = wg;      }
    int by = t >> gxs;
    int bx = t & ((1 << gxs) - 1);

    const unsigned short* Ab = A + (size_t)bz * batchA + (size_t)by * 128 * K;
    const unsigned short* Bb = B + (size_t)bz * batchB + (size_t)bx * 128 * K;
    TC* Cb = C + (size_t)bz * batchC;

    int lane = tid & 63;
    int wid = tid >> 6;
    int wr = wid >> 1, wc = wid & 1;
    int lr = lane & 15;
    int lk = (lane >> 4) * 8;

    f32x4 acc[4][4] = {};

    for (int k0 = 0; k0 < K; k0 += 32) {
#pragma unroll
        for (int c = 0; c < 2; ++c) {
            int t16 = c * 256 + tid;           // 16B chunk id within 8KB tile
            int row = t16 >> 2;
            int col = (t16 & 3) * 8;
            gload_lds16(Ab + (size_t)row * K + k0 + col, &sA[t16 * 8]);
            gload_lds16(Bb + (size_t)row * K + k0 + col, &sB[t16 * 8]);
        }
        __syncthreads();   // drains vmcnt (compiler emits full waitcnt before s_barrier)
        bf16x8 af[4], bfr[4];
#pragma unroll
        for (int m = 0; m < 4; ++m)
            af[m] = *reinterpret_cast<const bf16x8*>(&sA[(wr * 64 + m * 16 + lr) * 32 + lk]);
#pragma unroll
        for (int n = 0; n < 4; ++n)
            bfr[n] = *reinterpret_cast<const bf16x8*>(&sB[(wc * 64 + n * 16 + lr) * 32 + lk]);
#pragma unroll
        for (int m = 0; m < 4; ++m)
#pragma unroll
            for (int n = 0; n < 4; ++n)
                acc[m][n] = __builtin_amdgcn_mfma_f32_16x16x32_bf16(af[m], bfr[n], acc[m][n], 0, 0, 0);
        __syncthreads();
    }

    // C/D layout 16x16x32: col = lane&15, row = (lane>>4)*4 + j
#pragma unroll
    for (int m = 0; m < 4; ++m) {
        int r0 = by * 128 + wr * 64 + m * 16 + (lane >> 4) * 4;
#pragma unroll
        for (int n = 0; n < 4; ++n) {
            int c0 = bx * 128 + wc * 64 + n * 16 + (lane & 15);
#pragma unroll
            for (int j = 0; j < 4; ++j) {
                float v = acc[m][n][j] * scale;
                if constexpr (std::is_same_v<TC, float>)
                    Cb[(size_t)(r0 + j) * N + c0] = v;
                else
                    Cb[(size_t)(r0 + j) * N + c0] = f2bf(v);
            }
        }
    }
}

// ---------------- row softmax in place on bf16 [rows, L=2048] ----------------
__global__ __launch_bounds__(256) void softmax_inplace(unsigned short* __restrict__ S, int L) {
    __shared__ float red[8];
    size_t row = blockIdx.x;
    unsigned short* p = S + row * (size_t)L;
    int tid = threadIdx.x;
    int lane = tid & 63;
    int wid = tid >> 6;

    u16x8 u = *(const u16x8*)(p + tid * 8);
    float v[8];
#pragma unroll
    for (int j = 0; j < 8; ++j) v[j] = bf2f(u[j]);

    float mx = v[0];
#pragma unroll
    for (int j = 1; j < 8; ++j) mx = fmaxf(mx, v[j]);
#pragma unroll
    for (int off = 32; off > 0; off >>= 1) mx = fmaxf(mx, __shfl_xor(mx, off));
    if (lane == 0) red[wid] = mx;
    __syncthreads();
    mx = fmaxf(fmaxf(red[0], red[1]), fmaxf(red[2], red[3]));

    float s = 0.f;
#pragma unroll
    for (int j = 0; j < 8; ++j) { v[j] = __expf(v[j] - mx); s += v[j]; }
#pragma unroll
    for (int off = 32; off > 0; off >>= 1) s += __shfl_xor(s, off);
    if (lane == 0) red[4 + wid] = s;
    __syncthreads();
    s = red[4] + red[5] + red[6] + red[7];
    float inv = 1.0f / s;

    u16x8 o;
#pragma unroll
    for (int j = 0; j < 8; ++j) o[j] = f2bf(v[j] * inv);
    *(u16x8*)(p + tid * 8) = o;
}

extern "C" void kernel_launch(void* const* d_in, const int* in_sizes, int n_in,
                              void* d_out, int out_size, void* d_ws, size_t ws_size,
                              hipStream_t stream) {
    constexpr int B = 8, L = 2048, T = 1024, Dh = 1024, Dg = 768, Dp = 256;
    const float* H  = (const float*)d_in[0];
    const float* G  = (const float*)d_in[1];
    const float* Wq = (const float*)d_in[2];
    const float* Wk = (const float*)d_in[3];
    float* Z = (float*)d_out;

    unsigned short* Qbf  = (unsigned short*)d_ws;                 // B*T*Dp   =  2M
    unsigned short* Kbf  = Qbf  + (size_t)B * T * Dp;             // B*L*Dp   =  4M
    unsigned short* HT   = Kbf  + (size_t)B * L * Dp;             // B*Dh*L   = 16M
    unsigned short* HbfS = HT   + (size_t)B * Dh * L;             // max(Hbf, S) = 16M
    unsigned short* Gbf  = HbfS + (size_t)B * (size_t)T * L;      // B*T*Dg   =  6M
    unsigned short* Wqbf = Gbf  + (size_t)B * T * Dg;             // Dp*Dg
    unsigned short* Wkbf = Wqbf + (size_t)Dp * Dg;                // Dp*Dh

    // 1. casts
    cast_bf16<<<(B * T * Dg / 8 + 255) / 256, 256, 0, stream>>>(G, Gbf, B * T * Dg / 8);
    cast_bf16<<<(Dp * Dg / 8 + 255) / 256, 256, 0, stream>>>(Wq, Wqbf, Dp * Dg / 8);
    cast_bf16<<<(Dp * Dh / 8 + 255) / 256, 256, 0, stream>>>(Wk, Wkbf, Dp * Dh / 8);

    // 2. HT[b,d,l] + Hbf[b,l,d]
    transpose_cast<<<dim3(Dh / 32, L / 32, B), dim3(32, 8), 0, stream>>>(H, HT, HbfS, L, Dh);

    // 3. Q = Gbf @ Wqbf^T  [B*T, Dp], K=Dg; grid 2 x 64
    gemm_lds<unsigned short, false><<<(Dp / 128) * (B * T / 128), 256, 0, stream>>>
        (Gbf, Wqbf, Qbf, Dp, Dg, 0, 0, 0, 1.0f, 1);

    // 4. K = Hbf @ Wkbf^T  [B*L, Dp], K=Dh; grid 2 x 128
    gemm_lds<unsigned short, false><<<(Dp / 128) * (B * L / 128), 256, 0, stream>>>
        (HbfS, Wkbf, Kbf, Dp, Dh, 0, 0, 0, 1.0f, 1);

    // 5. S[b] = Q[b]@K[b]^T / 16  [T,L], K=Dp; grid 16 x 8 x 8 batches, XCD-clustered
    gemm_lds<unsigned short, true><<<(L / 128) * (T / 128) * B, 256, 0, stream>>>
        (Qbf, Kbf, HbfS, L, Dp, (long)T * Dp, (long)L * Dp, (long)T * L, 0.0625f, 4);

    // 6. softmax rows (in place)
    softmax_inplace<<<dim3(B * T), 256, 0, stream>>>(HbfS, L);

    // 7. Z[b] = P[b] @ HT[b]^T  [T,Dh], K=L; grid 8 x 8 x 8 batches, XCD-clustered
    gemm_lds<float, true><<<(Dh / 128) * (T / 128) * B, 256, 0, stream>>>
        (HbfS, HT, Z, Dh, L, (long)T * L, (long)Dh * L, (long)T * Dh, 1.0f, 3);
}